// Round 7
// baseline (2212.487 us; speedup 1.0000x reference)
//
#include <hip/hip_runtime.h>
#include <stdint.h>

// LSTM autoregressive rollout, batch-split persistent blocks.
// B=8192, HORIZON=64, F=64, ORDER=16, K=256, 4K=1024.
// R7: M=64 rows per block, 128 blocks, 512 threads (8 waves, 2/EU).
// Rationale: stalls are dominated by streamed-weight refill latency
// (~2-2.5k cyc effective under contention) that cannot be covered by any
// realizable buffer depth. Doubling M amortizes the same weight stream over
// 2x the work (16 -> 10 KB streamed per batch-row) and doubles per-block
// MFMA cover per refill wait. acc[4][8] (128 f32) rides the gfx950 unified
// AGPR file; 512-thread shape is the one the allocator gives 128 VGPRs.
// Weights: ks0 parked in LDS (64KB); ks 1..10 streamed, double-buffered,
// cross-step tail refill. Plain __syncthreads everywhere (R2 discipline).
// K rows layout: 0..63 = x_t, 64..79 = yp (newest first), 80..335 = h, 336..351 pad.

typedef short v8s __attribute__((ext_vector_type(8)));
typedef float v4f __attribute__((ext_vector_type(4)));

#define NKS 11          // 352/32 k-steps
#define NKCOL 1024      // 4K columns
#define MT 4            // 4 m-tiles of 16 rows = 64 rows/block

__device__ __forceinline__ unsigned bf16u(float f) {
  unsigned u = __float_as_uint(f);
  return (u + 0x7FFFu + ((u >> 16) & 1u)) >> 16;   // RNE fp32->bf16
}
__device__ __forceinline__ float sigm(float x) {
  return __builtin_amdgcn_rcpf(1.f + __expf(-x));
}
__device__ __forceinline__ float tanh_(float x) {
  return 1.f - 2.f * __builtin_amdgcn_rcpf(1.f + __expf(2.f * x));
}
// Swizzled A-LDS address for element (m, k): tiles of 1KB per (mt, ks),
// within tile lane-linear for the MFMA A-fragment read (lane*16B).
__device__ __forceinline__ int a_addr(int m, int k) {
  return (((m >> 4) * NKS + (k >> 5)) << 10)
       + ((((k >> 3) & 3) * 16 + (m & 15)) << 4)
       + ((k & 7) << 1);
}

// ---------------- weight swizzle prep (once per launch) ----------------
// Wsw[(nt*11 + ks)*64 + lane] = 8 bf16: B[k = ks*32 + (lane>>4)*8 + j][n = nt*16 + (lane&15)]
__global__ void prep_w(const float* __restrict__ ker, const float* __restrict__ rec,
                       uint4* __restrict__ wsw) {
  int tid = blockIdx.x * 256 + threadIdx.x;     // 0 .. 45055 (64 nt * 11 ks * 64 lanes)
  int lane = tid & 63;
  int rest = tid >> 6;
  int ks = rest % NKS;
  int nt = rest / NKS;
  int n  = nt * 16 + (lane & 15);
  int k0 = ks * 32 + ((lane >> 4) & 3) * 8;
  unsigned h[8];
  #pragma unroll
  for (int j = 0; j < 8; ++j) {
    int k = k0 + j;
    float v = 0.f;
    if (k < 80)       v = ker[k * NKCOL + n];          // x rows 0..63, yp rows 64..79
    else if (k < 336) v = rec[(k - 80) * NKCOL + n];   // h rows
    h[j] = bf16u(v);
  }
  uint4 o;
  o.x = h[0] | (h[1] << 16); o.y = h[2] | (h[3] << 16);
  o.z = h[4] | (h[5] << 16); o.w = h[6] | (h[7] << 16);
  wsw[tid] = o;
}

// ---------------- main persistent kernel ----------------
__global__ __launch_bounds__(512, 2)
void lstm_main(const float* __restrict__ x, const float* __restrict__ y0,
               const float* __restrict__ bias, const float* __restrict__ dw,
               const float* __restrict__ db, const v8s* __restrict__ wv,
               float* __restrict__ out) {
  __shared__ __align__(16) char a_lds[MT * NKS * 1024];  // 45056 B swizzled A (64 rows)
  __shared__ __align__(16) v8s w_lds[64 * 64];           // 65536 B parked W (ks 0)
  __shared__ float predbuf[64][8];
  __shared__ float predf[64];

  const int tid  = threadIdx.x;
  const int lane = tid & 63;
  const int wave = tid >> 6;          // 0..7 = n-tile group: units [wave*32,+32)
  const int l15  = lane & 15;
  const int quad = lane >> 4;
  const int b0   = blockIdx.x * 64;

  // zero A (h rows must be 0 at t=0; pad rows stay 0 forever)
  for (int i = tid; i < MT * NKS * 256; i += 512) ((unsigned*)a_lds)[i] = 0;
  // park W k-step 0 into LDS: w_lds[nt*64 + lane]
  for (int i = tid; i < 64 * 64; i += 512) {
    int nt = i >> 6, ln = i & 63;
    w_lds[i] = wv[(nt * NKS) * 64 + ln];
  }

  // per-lane constants: local ntile ln = gate*2+s -> global ntile = g*16 + wave*2 + s
  float bias_v[8];
  int wb[8], wlo[8];
  #pragma unroll
  for (int ln = 0; ln < 8; ++ln) {
    int g = ln >> 1, s = ln & 1;
    int ntg = g * 16 + wave * 2 + s;
    wb[ln]  = ntg * NKS * 64;
    wlo[ln] = ntg * 64 + lane;
    bias_v[ln] = bias[ntg * 16 + l15];
  }
  float dw_v[2];
  dw_v[0] = dw[wave * 32 + l15];
  dw_v[1] = dw[wave * 32 + 16 + l15];
  const float dbv = db[0];

  float cst[MT][2][4];          // c state: [mt][s][r]
  #pragma unroll
  for (int mt = 0; mt < MT; ++mt)
    #pragma unroll
    for (int s = 0; s < 2; ++s)
      #pragma unroll
      for (int r = 0; r < 4; ++r) cst[mt][s][r] = 0.f;

  #define REFILL(BUF, rks)                                                    \
    do {                                                                      \
      _Pragma("unroll")                                                       \
      for (int ln = 0; ln < 8; ++ln)                                          \
        BUF[ln] = wv[wb[ln] + (rks) * 64 + lane];                             \
    } while (0)

  // stream double-buffer prologue: ks 1, 2 in flight before first GEMM
  v8s bs0[8], bs1[8];
  REFILL(bs0, 1);
  REFILL(bs1, 2);

  // P1/P2 thread roles: all 512 threads serve both x (64 rows x 8) and yp.
  const int ms  = tid >> 3;            // 0..63 batch row
  const int kq8 = tid & 7;             // x: 8-float chunk; yp: pair index jj
  float4 xpa, xpb;
  {
    const float* xp = x + ((size_t)((b0 + ms) * 64)) * 64 + kq8 * 8;
    xpa = ((const float4*)xp)[0];
    xpb = ((const float4*)xp)[1];
  }

  __syncthreads();   // a_lds zero + w_lds park visible; prologue loads drained

  #pragma unroll 1
  for (int t = 0; t < 64; ++t) {
    // ---- P1: read phase (x in regs; yp olds / y0; prev pred) ----
    unsigned xw[4];
    xw[0] = bf16u(xpa.x) | (bf16u(xpa.y) << 16);
    xw[1] = bf16u(xpa.z) | (bf16u(xpa.w) << 16);
    xw[2] = bf16u(xpb.x) | (bf16u(xpb.y) << 16);
    xw[3] = bf16u(xpb.z) | (bf16u(xpb.w) << 16);
    unsigned short q0, q1;
    float pin = 0.f;
    if (t == 0) {
      q0 = (unsigned short)bf16u(y0[(b0 + ms) * 16 + 2 * kq8]);
      q1 = (unsigned short)bf16u(y0[(b0 + ms) * 16 + 2 * kq8 + 1]);
    } else {
      q0 = *(const unsigned short*)(a_lds + a_addr(ms, 64 + 2 * kq8));
      q1 = *(const unsigned short*)(a_lds + a_addr(ms, 64 + 2 * kq8 + 1));
      pin = predf[ms];
    }
    __syncthreads();
    // ---- P2: write phase ----
    {
      uint4 w4; w4.x = xw[0]; w4.y = xw[1]; w4.z = xw[2]; w4.w = xw[3];
      *(uint4*)(a_lds + a_addr(ms, kq8 * 8)) = w4;
    }
    if (t == 0) {
      *(unsigned short*)(a_lds + a_addr(ms, 64 + 2 * kq8))     = q0;
      *(unsigned short*)(a_lds + a_addr(ms, 64 + 2 * kq8 + 1)) = q1;
    } else {
      if (kq8 < 7) {
        *(unsigned short*)(a_lds + a_addr(ms, 64 + 2 * kq8 + 1)) = q0;
        *(unsigned short*)(a_lds + a_addr(ms, 64 + 2 * kq8 + 2)) = q1;
      } else {
        *(unsigned short*)(a_lds + a_addr(ms, 79)) = q0;   // j=14 -> 15
      }
      if (kq8 == 0)
        *(unsigned short*)(a_lds + a_addr(ms, 64)) = (unsigned short)bf16u(pin);
    }
    __syncthreads();

    // ---- P3: GEMM  z[64,1024] += inp[64,352] @ W[352,1024] ----
    v4f acc[MT][8];
    #pragma unroll
    for (int mt = 0; mt < MT; ++mt)
      #pragma unroll
      for (int ln = 0; ln < 8; ++ln) acc[mt][ln] = v4f{0.f, 0.f, 0.f, 0.f};

    v8s af[MT];
    #pragma unroll
    for (int mt = 0; mt < MT; ++mt)
      af[mt] = *(const v8s*)(a_lds + ((mt * NKS) << 10) + (lane << 4));

    // A-fragment prefetch + 32 MFMA (4 mt x 8 ln) on weight fragments W8.
    #define MFMA_BLK(ksi, W8)                                                   \
      do {                                                                      \
        v8s c0 = af[0], c1 = af[1], c2 = af[2], c3 = af[3];                     \
        if ((ksi) < NKS - 1) {                                                  \
          _Pragma("unroll")                                                     \
          for (int mt = 0; mt < MT; ++mt)                                       \
            af[mt] = *(const v8s*)(a_lds + ((mt * NKS + (ksi) + 1) << 10) + (lane << 4)); \
        }                                                                       \
        _Pragma("unroll")                                                       \
        for (int ln = 0; ln < 8; ++ln) {                                        \
          acc[0][ln] = __builtin_amdgcn_mfma_f32_16x16x32_bf16(c0, W8[ln], acc[0][ln], 0, 0, 0); \
          acc[1][ln] = __builtin_amdgcn_mfma_f32_16x16x32_bf16(c1, W8[ln], acc[1][ln], 0, 0, 0); \
          acc[2][ln] = __builtin_amdgcn_mfma_f32_16x16x32_bf16(c2, W8[ln], acc[2][ln], 0, 0, 0); \
          acc[3][ln] = __builtin_amdgcn_mfma_f32_16x16x32_bf16(c3, W8[ln], acc[3][ln], 0, 0, 0); \
        }                                                                       \
      } while (0)

    // ks0: LDS-parked weights
    {
      v8s wl[8];
      #pragma unroll
      for (int ln = 0; ln < 8; ++ln) wl[ln] = w_lds[wlo[ln]];
      MFMA_BLK(0, wl);
    }
    // streamed ks 1..10: consume-then-refill at distance 2; tail refills load
    // NEXT STEP's ks1/ks2 (drained at the barrier -> ready at next GEMM start).
    MFMA_BLK(1, bs0);   REFILL(bs0, 3);
    MFMA_BLK(2, bs1);   REFILL(bs1, 4);
    MFMA_BLK(3, bs0);   REFILL(bs0, 5);
    MFMA_BLK(4, bs1);   REFILL(bs1, 6);
    MFMA_BLK(5, bs0);   REFILL(bs0, 7);
    MFMA_BLK(6, bs1);   REFILL(bs1, 8);
    MFMA_BLK(7, bs0);   REFILL(bs0, 9);
    MFMA_BLK(8, bs1);   REFILL(bs1, 10);
    MFMA_BLK(9, bs0);   REFILL(bs0, 1);    // next-step ks1
    MFMA_BLK(10, bs1);  REFILL(bs1, 2);    // next-step ks2

    #undef MFMA_BLK

    __syncthreads();   // all A reads done before h-row writes

    // x_{t+1} prefetch: post-GEMM so it never head-of-line blocks weight
    // waits (in-order vmcnt); covered by P4 VALU work.
    if (t < 63) {
      const float* xp = x + ((size_t)((b0 + ms) * 64 + (t + 1))) * 64 + kq8 * 8;
      xpa = ((const float4*)xp)[0];
      xpb = ((const float4*)xp)[1];
    }

    // ---- P4: gates, c/h update, h->A, pred partials ----
    float padd[MT][4];
    #pragma unroll
    for (int mt = 0; mt < MT; ++mt)
      #pragma unroll
      for (int r = 0; r < 4; ++r) padd[mt][r] = 0.f;

    #pragma unroll
    for (int mt = 0; mt < MT; ++mt) {
      #pragma unroll
      for (int s = 0; s < 2; ++s) {
        const int kk = 80 + wave * 32 + s * 16 + l15;    // h row in A
        #pragma unroll
        for (int r = 0; r < 4; ++r) {
          float zi = acc[mt][0 + s][r] + bias_v[0 + s];
          float zf = acc[mt][2 + s][r] + bias_v[2 + s];
          float zg = acc[mt][4 + s][r] + bias_v[4 + s];
          float zo = acc[mt][6 + s][r] + bias_v[6 + s];
          float is = sigm(zi), fs = sigm(zf), gs = tanh_(zg), os = sigm(zo);
          float cn = fs * cst[mt][s][r] + is * gs;
          cst[mt][s][r] = cn;
          float hh = os * tanh_(cn);
          int m = mt * 16 + quad * 4 + r;
          *(unsigned short*)(a_lds + a_addr(m, kk)) = (unsigned short)bf16u(hh);
          padd[mt][r] += hh * dw_v[s];
        }
      }
    }
    // reduce pred partial over the 16-lane column group
    #pragma unroll
    for (int mt = 0; mt < MT; ++mt) {
      #pragma unroll
      for (int r = 0; r < 4; ++r) {
        float p = padd[mt][r];
        p += __shfl_xor(p, 1);
        p += __shfl_xor(p, 2);
        p += __shfl_xor(p, 4);
        p += __shfl_xor(p, 8);
        if (l15 == 0) predbuf[mt * 16 + quad * 4 + r][wave] = p;
      }
    }
    __syncthreads();
    // ---- P5: finalize pred, write output ----
    if (tid < 64) {
      float p = dbv;
      #pragma unroll
      for (int w = 0; w < 8; ++w) p += predbuf[tid][w];
      out[(size_t)(b0 + tid) * 64 + t] = p;
      predf[tid] = p;
    }
    __syncthreads();
  }
  #undef REFILL
}

extern "C" void kernel_launch(void* const* d_in, const int* in_sizes, int n_in,
                              void* d_out, int out_size, void* d_ws, size_t ws_size,
                              hipStream_t stream) {
  const float* x    = (const float*)d_in[0];
  const float* y0   = (const float*)d_in[1];
  const float* ker  = (const float*)d_in[2];
  const float* rec  = (const float*)d_in[3];
  const float* bias = (const float*)d_in[4];
  const float* dw   = (const float*)d_in[5];
  const float* db   = (const float*)d_in[6];

  // swizzled weights: 64 ntiles * 11 ksteps * 64 lanes * 16B = 720896 B in d_ws
  prep_w<<<dim3(176), dim3(256), 0, stream>>>(ker, rec, (uint4*)d_ws);
  lstm_main<<<dim3(128), dim3(512), 0, stream>>>(x, y0, bias, dw, db,
                                                 (const v8s*)d_ws, (float*)d_out);
}

// Round 8
// 1504.658 us; speedup vs baseline: 1.4704x; 1.4704x over previous
//
#include <hip/hip_runtime.h>
#include <stdint.h>

// LSTM autoregressive rollout, batch-split persistent blocks.
// B=8192, HORIZON=64, F=64, ORDER=16, K=256, 4K=1024.
// Block = 32 batch rows, 512 threads (8 waves, 2/SIMD). 256 blocks = 1/CU.
// R8 = R2 structure with ZERO register spill + zero write pollution:
//  - PKR=0: no reg-parked weights. ks0..1 parked in LDS (128KB); ks2..10
//    streamed (576KB/step), double-buffered in bs0/bs1, cross-step tail refill.
//  - LDS-parked MFMA blocks read weight fragments inline (2-3 reg window).
//  - x_{t+1} prefetch AFTER the GEMM (xpa/xpb dead across the GEMM peak).
//  - out stores buffered 16 steps in LDS, flushed as full 64B lines.
//  Rationale: dur tracks FETCH/~3.1TB/s; the 720KB weight cycle fits L2 5x,
//  yet ~39% missed. Miss rate correlates with WRITE_SIZE (scratch spill)
//  across all rounds -> spill traffic was evicting the weight stream.
// K rows layout: 0..63 = x_t, 64..79 = yp (newest first), 80..335 = h, 336..351 pad.

typedef short v8s __attribute__((ext_vector_type(8)));
typedef float v4f __attribute__((ext_vector_type(4)));

#define NKS 11          // 352/32 k-steps
#define NKCOL 1024      // 4K columns
#define PKL 2           // k-steps parked in LDS (ks 0..1)
#define SK0 PKL         // first streamed k-step (2)

__device__ __forceinline__ unsigned bf16u(float f) {
  unsigned u = __float_as_uint(f);
  return (u + 0x7FFFu + ((u >> 16) & 1u)) >> 16;   // RNE fp32->bf16
}
__device__ __forceinline__ float sigm(float x) {
  return __builtin_amdgcn_rcpf(1.f + __expf(-x));
}
__device__ __forceinline__ float tanh_(float x) {
  return 1.f - 2.f * __builtin_amdgcn_rcpf(1.f + __expf(2.f * x));
}
// Swizzled A-LDS address for element (m, k): tiles of 1KB per (mt, ks),
// within tile lane-linear for the MFMA A-fragment read (lane*16B).
__device__ __forceinline__ int a_addr(int m, int k) {
  return (((m >> 4) * NKS + (k >> 5)) << 10)
       + ((((k >> 3) & 3) * 16 + (m & 15)) << 4)
       + ((k & 7) << 1);
}

// ---------------- weight swizzle prep (once per launch) ----------------
// Wsw[(nt*11 + ks)*64 + lane] = 8 bf16: B[k = ks*32 + (lane>>4)*8 + j][n = nt*16 + (lane&15)]
__global__ void prep_w(const float* __restrict__ ker, const float* __restrict__ rec,
                       uint4* __restrict__ wsw) {
  int tid = blockIdx.x * 256 + threadIdx.x;     // 0 .. 45055 (64 nt * 11 ks * 64 lanes)
  int lane = tid & 63;
  int rest = tid >> 6;
  int ks = rest % NKS;
  int nt = rest / NKS;
  int n  = nt * 16 + (lane & 15);
  int k0 = ks * 32 + ((lane >> 4) & 3) * 8;
  unsigned h[8];
  #pragma unroll
  for (int j = 0; j < 8; ++j) {
    int k = k0 + j;
    float v = 0.f;
    if (k < 80)       v = ker[k * NKCOL + n];          // x rows 0..63, yp rows 64..79
    else if (k < 336) v = rec[(k - 80) * NKCOL + n];   // h rows
    h[j] = bf16u(v);
  }
  uint4 o;
  o.x = h[0] | (h[1] << 16); o.y = h[2] | (h[3] << 16);
  o.z = h[4] | (h[5] << 16); o.w = h[6] | (h[7] << 16);
  wsw[tid] = o;
}

// ---------------- main persistent kernel ----------------
__global__ __launch_bounds__(512, 2)
void lstm_main(const float* __restrict__ x, const float* __restrict__ y0,
               const float* __restrict__ bias, const float* __restrict__ dw,
               const float* __restrict__ db, const v8s* __restrict__ wv,
               float* __restrict__ out) {
  __shared__ __align__(16) char a_lds[2 * NKS * 1024];   // 22528 B swizzled A
  __shared__ __align__(16) v8s w_lds[PKL * 64 * 64];     // 131072 B parked W (ks 0..1)
  __shared__ float predbuf[32][8];
  __shared__ __align__(16) float predall[32][16];        // 16-step out buffer
  __shared__ float predf[32];

  const int tid  = threadIdx.x;
  const int lane = tid & 63;
  const int wave = tid >> 6;
  const int l15  = lane & 15;
  const int quad = lane >> 4;
  const int b0   = blockIdx.x * 32;

  // zero A (h rows must be 0 at t=0; pad rows stay 0 forever)
  for (int i = tid; i < 2 * NKS * 256; i += 512) ((unsigned*)a_lds)[i] = 0;
  // park W k-steps 0..1 into LDS: w_lds[ksl*4096 + nt*64 + lane]
  for (int i = tid; i < PKL * 64 * 64; i += 512) {
    int ksl = i >> 12;
    int nt  = (i >> 6) & 63;
    int ln  = i & 63;
    w_lds[i] = wv[(nt * NKS + ksl) * 64 + ln];
  }

  // per-lane constants: wave owns hidden units [wave*32, wave*32+32)
  // local ntile ln = gate*2 + s  ->  global ntile = gate*16 + wave*2 + s
  float bias_v[8];
  int wb[8], wlo[8];
  #pragma unroll
  for (int ln = 0; ln < 8; ++ln) {
    int g = ln >> 1, s = ln & 1;
    int ntg = g * 16 + wave * 2 + s;
    wb[ln]  = ntg * NKS * 64;
    wlo[ln] = ntg * 64 + lane;
    bias_v[ln] = bias[ntg * 16 + l15];
  }
  float dw_v[2];
  dw_v[0] = dw[wave * 32 + l15];
  dw_v[1] = dw[wave * 32 + 16 + l15];
  const float dbv = db[0];

  float cst[2][2][4];           // c state: [mt][s][r]
  #pragma unroll
  for (int mt = 0; mt < 2; ++mt)
    #pragma unroll
    for (int s = 0; s < 2; ++s)
      #pragma unroll
      for (int r = 0; r < 4; ++r) cst[mt][s][r] = 0.f;

  #define REFILL(BUF, rks)                                                    \
    do {                                                                      \
      _Pragma("unroll")                                                       \
      for (int ln = 0; ln < 8; ++ln)                                          \
        BUF[ln] = wv[wb[ln] + (rks) * 64 + lane];                             \
    } while (0)

  // stream double-buffer prologue: ks 2, 3 in flight before first GEMM
  v8s bs0[8], bs1[8];
  REFILL(bs0, SK0);
  REFILL(bs1, SK0 + 1);

  // x prefetch for t=0 (waves 0-3)
  const int ms_x  = tid >> 3;          // valid for tid < 256
  const int kq8_x = tid & 7;
  const int ms_y  = (tid - 256) >> 3;  // valid for tid >= 256
  const int jj    = tid & 7;
  float4 xpa, xpb;
  if (tid < 256) {
    const float* xp = x + ((size_t)((b0 + ms_x) * 64)) * 64 + kq8_x * 8;
    xpa = ((const float4*)xp)[0];
    xpb = ((const float4*)xp)[1];
  }

  __syncthreads();   // a_lds zero + w_lds park visible; prologue loads drained

  #pragma unroll 1
  for (int t = 0; t < 64; ++t) {
    // ---- P1: read phase (x in regs; yp olds / y0; prev pred) ----
    unsigned xw[4];
    unsigned short q0 = 0, q1 = 0;
    float pin = 0.f;
    if (tid < 256) {                       // waves 0-3: convert prefetched x_t
      xw[0] = bf16u(xpa.x) | (bf16u(xpa.y) << 16);
      xw[1] = bf16u(xpa.z) | (bf16u(xpa.w) << 16);
      xw[2] = bf16u(xpb.x) | (bf16u(xpb.y) << 16);
      xw[3] = bf16u(xpb.z) | (bf16u(xpb.w) << 16);
    } else {                               // waves 4-7: yp shift / init
      if (t == 0) {
        q0 = (unsigned short)bf16u(y0[(b0 + ms_y) * 16 + 2 * jj]);
        q1 = (unsigned short)bf16u(y0[(b0 + ms_y) * 16 + 2 * jj + 1]);
      } else {
        q0 = *(const unsigned short*)(a_lds + a_addr(ms_y, 64 + 2 * jj));
        q1 = *(const unsigned short*)(a_lds + a_addr(ms_y, 64 + 2 * jj + 1));
        pin = predf[ms_y];
      }
    }
    __syncthreads();
    // ---- P2: write phase ----
    if (tid < 256) {
      uint4 w4; w4.x = xw[0]; w4.y = xw[1]; w4.z = xw[2]; w4.w = xw[3];
      *(uint4*)(a_lds + a_addr(ms_x, kq8_x * 8)) = w4;
    } else {
      if (t == 0) {
        *(unsigned short*)(a_lds + a_addr(ms_y, 64 + 2 * jj))     = q0;
        *(unsigned short*)(a_lds + a_addr(ms_y, 64 + 2 * jj + 1)) = q1;
      } else {
        if (jj < 7) {
          *(unsigned short*)(a_lds + a_addr(ms_y, 64 + 2 * jj + 1)) = q0;
          *(unsigned short*)(a_lds + a_addr(ms_y, 64 + 2 * jj + 2)) = q1;
        } else {
          *(unsigned short*)(a_lds + a_addr(ms_y, 79)) = q0;   // j=14 -> 15
        }
        if (jj == 0)
          *(unsigned short*)(a_lds + a_addr(ms_y, 64)) = (unsigned short)bf16u(pin);
      }
    }
    __syncthreads();

    // ---- P3: GEMM  z[32,1024] += inp[32,352] @ W[352,1024] ----
    v4f acc[2][8];
    #pragma unroll
    for (int mt = 0; mt < 2; ++mt)
      #pragma unroll
      for (int ln = 0; ln < 8; ++ln) acc[mt][ln] = v4f{0.f, 0.f, 0.f, 0.f};

    v8s af0 = *(const v8s*)(a_lds + (lane << 4));
    v8s af1 = *(const v8s*)(a_lds + (NKS << 10) + (lane << 4));

    // A-fragment prefetch + 16 MFMA on weight fragments W8, for tile ks.
    #define MFMA_BLK(ksi, W8)                                                   \
      do {                                                                      \
        v8s c0 = af0, c1 = af1;                                                 \
        if ((ksi) < NKS - 1) {                                                  \
          af0 = *(const v8s*)(a_lds + (((ksi) + 1) << 10) + (lane << 4));       \
          af1 = *(const v8s*)(a_lds + ((NKS + (ksi) + 1) << 10) + (lane << 4)); \
        }                                                                       \
        _Pragma("unroll")                                                       \
        for (int ln = 0; ln < 8; ++ln) {                                        \
          acc[0][ln] = __builtin_amdgcn_mfma_f32_16x16x32_bf16(c0, W8[ln], acc[0][ln], 0, 0, 0); \
          acc[1][ln] = __builtin_amdgcn_mfma_f32_16x16x32_bf16(c1, W8[ln], acc[1][ln], 0, 0, 0); \
        }                                                                       \
      } while (0)
    // LDS-parked block: weight fragments read inline, 1 live at a time.
    #define MFMA_BLK_LDS(ksi, OFF)                                              \
      do {                                                                      \
        v8s c0 = af0, c1 = af1;                                                 \
        af0 = *(const v8s*)(a_lds + (((ksi) + 1) << 10) + (lane << 4));         \
        af1 = *(const v8s*)(a_lds + ((NKS + (ksi) + 1) << 10) + (lane << 4));   \
        _Pragma("unroll")                                                       \
        for (int ln = 0; ln < 8; ++ln) {                                        \
          v8s w = w_lds[(OFF) + wlo[ln]];                                       \
          acc[0][ln] = __builtin_amdgcn_mfma_f32_16x16x32_bf16(c0, w, acc[0][ln], 0, 0, 0); \
          acc[1][ln] = __builtin_amdgcn_mfma_f32_16x16x32_bf16(c1, w, acc[1][ln], 0, 0, 0); \
        }                                                                       \
      } while (0)

    MFMA_BLK_LDS(0, 0);
    MFMA_BLK_LDS(1, 4096);
    // streamed ks 2..10: consume-then-refill at distance 2; tail refills load
    // NEXT STEP's ks2/ks3 (drained at the barrier -> ready at next GEMM start).
    MFMA_BLK(2, bs0);   REFILL(bs0, 4);
    MFMA_BLK(3, bs1);   REFILL(bs1, 5);
    MFMA_BLK(4, bs0);   REFILL(bs0, 6);
    MFMA_BLK(5, bs1);   REFILL(bs1, 7);
    MFMA_BLK(6, bs0);   REFILL(bs0, 8);
    MFMA_BLK(7, bs1);   REFILL(bs1, 9);
    MFMA_BLK(8, bs0);   REFILL(bs0, 10);
    MFMA_BLK(9, bs1);   REFILL(bs1, SK0 + 1);   // next-step ks3
    MFMA_BLK(10, bs0);  REFILL(bs0, SK0);       // next-step ks2

    #undef MFMA_BLK
    #undef MFMA_BLK_LDS

    __syncthreads();   // all A reads done before h-row writes

    // x_{t+1} prefetch: post-GEMM so xpa/xpb are dead across the GEMM register
    // peak and never head-of-line block weight waits (in-order vmcnt).
    if (t < 63 && tid < 256) {
      const float* xp = x + ((size_t)((b0 + ms_x) * 64 + (t + 1))) * 64 + kq8_x * 8;
      xpa = ((const float4*)xp)[0];
      xpb = ((const float4*)xp)[1];
    }

    // ---- P4: gates, c/h update, h->A, pred partials ----
    float padd[2][4];
    #pragma unroll
    for (int mt = 0; mt < 2; ++mt)
      #pragma unroll
      for (int r = 0; r < 4; ++r) padd[mt][r] = 0.f;

    #pragma unroll
    for (int mt = 0; mt < 2; ++mt) {
      #pragma unroll
      for (int s = 0; s < 2; ++s) {
        const int kk = 80 + wave * 32 + s * 16 + l15;    // h row in A
        #pragma unroll
        for (int r = 0; r < 4; ++r) {
          float zi = acc[mt][0 + s][r] + bias_v[0 + s];
          float zf = acc[mt][2 + s][r] + bias_v[2 + s];
          float zg = acc[mt][4 + s][r] + bias_v[4 + s];
          float zo = acc[mt][6 + s][r] + bias_v[6 + s];
          float is = sigm(zi), fs = sigm(zf), gs = tanh_(zg), os = sigm(zo);
          float cn = fs * cst[mt][s][r] + is * gs;
          cst[mt][s][r] = cn;
          float hh = os * tanh_(cn);
          int m = mt * 16 + quad * 4 + r;
          *(unsigned short*)(a_lds + a_addr(m, kk)) = (unsigned short)bf16u(hh);
          padd[mt][r] += hh * dw_v[s];
        }
      }
    }
    // reduce pred partial over the 16-lane column group
    #pragma unroll
    for (int mt = 0; mt < 2; ++mt) {
      #pragma unroll
      for (int r = 0; r < 4; ++r) {
        float p = padd[mt][r];
        p += __shfl_xor(p, 1);
        p += __shfl_xor(p, 2);
        p += __shfl_xor(p, 4);
        p += __shfl_xor(p, 8);
        if (l15 == 0) predbuf[mt * 16 + quad * 4 + r][wave] = p;
      }
    }
    __syncthreads();
    // ---- P5: finalize pred into LDS (no per-step HBM store) ----
    if (tid < 32) {
      float p = dbv;
      #pragma unroll
      for (int w = 0; w < 8; ++w) p += predbuf[tid][w];
      predall[tid][t & 15] = p;
      predf[tid] = p;
    }
    __syncthreads();
    // flush 16 accumulated steps as full 64B lines (4x per rollout)
    if ((t & 15) == 15 && tid < 128) {
      int row = tid >> 2, c4 = (tid & 3) << 2;
      float4 v = *(const float4*)&predall[row][c4];
      *(float4*)&out[(size_t)(b0 + row) * 64 + (t - 15) + c4] = v;
    }
  }
  #undef REFILL
}

extern "C" void kernel_launch(void* const* d_in, const int* in_sizes, int n_in,
                              void* d_out, int out_size, void* d_ws, size_t ws_size,
                              hipStream_t stream) {
  const float* x    = (const float*)d_in[0];
  const float* y0   = (const float*)d_in[1];
  const float* ker  = (const float*)d_in[2];
  const float* rec  = (const float*)d_in[3];
  const float* bias = (const float*)d_in[4];
  const float* dw   = (const float*)d_in[5];
  const float* db   = (const float*)d_in[6];

  // swizzled weights: 64 ntiles * 11 ksteps * 64 lanes * 16B = 720896 B in d_ws
  prep_w<<<dim3(176), dim3(256), 0, stream>>>(ker, rec, (uint4*)d_ws);
  lstm_main<<<dim3(256), dim3(512), 0, stream>>>(x, y0, bias, dw, db,
                                                 (const v8s*)d_ws, (float*)d_out);
}